// Round 1
// baseline (209.226 us; speedup 1.0000x reference)
//
#include <hip/hip_runtime.h>

typedef __attribute__((ext_vector_type(8))) short bf16x8;
typedef __attribute__((ext_vector_type(4))) float f32x4;

#define DEVINL __device__ __forceinline__

constexpr int NI = 256;   // input channels
constexpr int NO = 256;   // output channels
constexpr int NC = 120;   // irrep feature width
constexpr int KH = 128;   // K half staged per LDS fill

constexpr int W0_ELEMS = 32 * NO * NI;
constexpr int W1_ELEMS = 16 * NO * NI;
constexpr int W2_ELEMS = 8 * NO * NI;
constexpr int WELEMS = W0_ELEMS + W1_ELEMS + W2_ELEMS;  // 3,670,016 -> needs 7.34 MB of d_ws

DEVINL ushort f2bf(float x) {   // round-to-nearest-even fp32 -> bf16 bits (inputs finite)
  unsigned u = __float_as_uint(x);
  u += 0x7FFFu + ((u >> 16) & 1u);
  return (ushort)(u >> 16);
}

// column c -> global weight-matrix id (0..55)
constexpr int mat_of(int c) {
  return c < 32 ? c : (c < 80 ? 32 + (c - 32) / 3 : 48 + (c - 80) / 5);
}

// ---- prep: concat W0|W1|W2 converted to bf16 into workspace, layout [56][256 o][256 i] ----
__global__ __launch_bounds__(256) void prep_w(const float* __restrict__ w0,
                                              const float* __restrict__ w1,
                                              const float* __restrict__ w2,
                                              ushort* __restrict__ wb) {
  int t = blockIdx.x * 256 + threadIdx.x;
  int e = t * 4;
  if (e >= WELEMS) return;
  const float* src;
  if (e < W0_ELEMS) src = w0 + e;
  else if (e < W0_ELEMS + W1_ELEMS) src = w1 + (e - W0_ELEMS);
  else src = w2 + (e - W0_ELEMS - W1_ELEMS);
  float4 v = *reinterpret_cast<const float4*>(src);
  ushort4 p;
  p.x = f2bf(v.x); p.y = f2bf(v.y); p.z = f2bf(v.z); p.w = f2bf(v.w);
  *reinterpret_cast<ushort4*>(wb + e) = p;
}

// ---- main: block = [16 b] x [128 o (half)] x [CW c-tile], K streamed in 2 halves via LDS ----
template<int CT>
DEVINL void tile_body(const float* __restrict__ x, const ushort* __restrict__ wb,
                      const float* __restrict__ bias0, float* __restrict__ out,
                      int bt, int oh, ushort* xs) {
  constexpr int c0 = CT * 16;
  constexpr int CW = (CT == 7) ? 8 : 16;   // c-tile 7 covers only c 112..119

  const int tid  = threadIdx.x;
  const int lane = tid & 63;
  const int wid  = tid >> 6;               // 8 waves, each owns 16 o-columns
  const int bg   = bt * 16;
  const int ocol = oh * 128 + wid * 16 + (lane & 15);

  const int rb = lane & 15;                // A-frag row (b)
  const int rg = lane >> 4;                // A/B-frag k-group

  // staging map: lane-contiguous c for coalesced 64B-line global reads
  const int sc   = tid & 15;               // c within tile
  const int sb   = (tid >> 4) & 15;        // b row
  const int sseg = tid >> 8;               // k segment (64 k each)

  f32x4 acc[CW];
#pragma unroll
  for (int i = 0; i < CW; ++i) acc[i] = (f32x4)0.0f;

#pragma unroll 1
  for (int kh = 0; kh < 2; ++kh) {
    if (kh) __syncthreads();               // protect LDS reuse
    if (sc < CW) {
      const float* src = x + (size_t)(bg + sb) * (NI * NC)
                           + (size_t)(kh * KH + sseg * 64) * NC + (c0 + sc);
      const int swz = ((sb & 7) ^ (sc & 7)) << 3;       // XOR bank swizzle on k
      ushort* dst = xs + ((sc * 16 + sb) << 7);         // plane [c][b][128 k]
#pragma unroll 4
      for (int jq = 0; jq < 16; ++jq) {
        float v0 = src[(4 * jq + 0) * NC];
        float v1 = src[(4 * jq + 1) * NC];
        float v2 = src[(4 * jq + 2) * NC];
        float v3 = src[(4 * jq + 3) * NC];
        int kpos = (sseg * 64 + 4 * jq) ^ swz;
        ushort4 p; p.x = f2bf(v0); p.y = f2bf(v1); p.z = f2bf(v2); p.w = f2bf(v3);
        *reinterpret_cast<ushort4*>(dst + kpos) = p;
      }
    }
    __syncthreads();

    bf16x8 bfr[4];                          // current W fragments (k-chunks of this K-half)
#pragma unroll
    for (int cc = 0; cc < CW; ++cc) {
      const int c = c0 + cc;
      const int m = mat_of(c);
      const bool newm = (cc == 0) || (mat_of(c - 1) != m);   // folds at compile time
      if (newm) {
        const ushort* wp = wb + ((size_t)(m * NO + ocol) << 8) + kh * KH + (rg << 3);
#pragma unroll
        for (int ks = 0; ks < 4; ++ks)
          bfr[ks] = *reinterpret_cast<const bf16x8*>(wp + ks * 32);
      }
      const ushort* xp = xs + ((cc * 16 + rb) << 7);
      const int swzr = ((rb & 7) ^ (cc & 7)) << 3;
#pragma unroll
      for (int ks = 0; ks < 4; ++ks) {
        bf16x8 a = *reinterpret_cast<const bf16x8*>(xp + ((ks * 32 + (rg << 3)) ^ swzr));
        acc[cc] = __builtin_amdgcn_mfma_f32_16x16x32_bf16(a, bfr[ks], acc[cc], 0, 0, 0);
      }
    }
  }

  if (CT < 2) {                             // l=0 irreps (c<32) carry bias b0[m=c][o]
#pragma unroll
    for (int cc = 0; cc < CW; ++cc) {
      float bv = bias0[(c0 + cc) * NO + ocol];
      acc[cc] += bv;
    }
  }

  const int br0 = bg + rg * 4;              // D row = (lane>>4)*4 + reg
#pragma unroll
  for (int r = 0; r < 4; ++r) {
#pragma unroll
    for (int q = 0; q < CW / 4; ++q) {      // 16B stores; thread owns full 64B c-line
      float4 v = make_float4(acc[4 * q + 0][r], acc[4 * q + 1][r],
                             acc[4 * q + 2][r], acc[4 * q + 3][r]);
      float* dst = out + ((size_t)(br0 + r) * NO + ocol) * NC + (c0 + 4 * q);
      *reinterpret_cast<float4*>(dst) = v;
    }
  }
}

__global__ __launch_bounds__(512, 4) void e3mix(const float* __restrict__ x,
                                                const ushort* __restrict__ wb,
                                                const float* __restrict__ bias0,
                                                float* __restrict__ out) {
  __shared__ ushort xs[16 * 16 * 128];      // 64 KB -> 2 blocks/CU
  const int bid = blockIdx.x;
  const int ct = bid & 7;                   // fastest -> per-XCD W locality (bid%8 ~ XCD)
  const int oh = (bid >> 3) & 1;
  const int bt = bid >> 4;                  // slowest -> b-slice temporal locality for x
  switch (ct) {
    case 0: tile_body<0>(x, wb, bias0, out, bt, oh, xs); break;
    case 1: tile_body<1>(x, wb, bias0, out, bt, oh, xs); break;
    case 2: tile_body<2>(x, wb, bias0, out, bt, oh, xs); break;
    case 3: tile_body<3>(x, wb, bias0, out, bt, oh, xs); break;
    case 4: tile_body<4>(x, wb, bias0, out, bt, oh, xs); break;
    case 5: tile_body<5>(x, wb, bias0, out, bt, oh, xs); break;
    case 6: tile_body<6>(x, wb, bias0, out, bt, oh, xs); break;
    default: tile_body<7>(x, wb, bias0, out, bt, oh, xs); break;
  }
}

extern "C" void kernel_launch(void* const* d_in, const int* in_sizes, int n_in,
                              void* d_out, int out_size, void* d_ws, size_t ws_size,
                              hipStream_t stream) {
  const float* x  = (const float*)d_in[0];
  const float* w0 = (const float*)d_in[1];
  const float* w1 = (const float*)d_in[2];
  const float* w2 = (const float*)d_in[3];
  const float* b0 = (const float*)d_in[4];
  float* out = (float*)d_out;
  ushort* wb = (ushort*)d_ws;               // needs 7.34 MB of scratch

  prep_w<<<WELEMS / 4 / 256, 256, 0, stream>>>(w0, w1, w2, wb);
  e3mix<<<1024, 512, 0, stream>>>(x, wb, b0, out);
}

// Round 2
// 197.987 us; speedup vs baseline: 1.0568x; 1.0568x over previous
//
#include <hip/hip_runtime.h>

typedef __attribute__((ext_vector_type(8))) short bf16x8;
typedef __attribute__((ext_vector_type(4))) float f32x4;
typedef __attribute__((ext_vector_type(8))) unsigned short u16x8;

#define DEVINL __device__ __forceinline__

constexpr int NI = 256;   // input channels (K)
constexpr int NO = 256;   // output channels
constexpr int NC = 120;   // irrep feature width
constexpr int KQ = 64;    // K staged per LDS fill
constexpr int NSTAGE = NI / KQ;   // 4

DEVINL ushort f2bf(float x) {   // round-to-nearest-even fp32 -> bf16 bits (inputs finite)
  unsigned u = __float_as_uint(x);
  u += 0x7FFFu + ((u >> 16) & 1u);
  return (ushort)(u >> 16);
}

// column c -> global weight-matrix id (0..55)
constexpr int mat_of(int c) {
  return c < 32 ? c : (c < 80 ? 32 + (c - 32) / 3 : 48 + (c - 80) / 5);
}

// ---- prep: wb[((m*32 + k/8)*256 + o)*8 + k%8] = bf16(W_m[o][k]) ----
// Fragment-major layout: a wave's B-fragment load (16 o x 8 k) is 4 contiguous
// 256B segments -> 100% cache-line utilization (was 512B-strided, 64 lines/instr).
__global__ __launch_bounds__(256) void prep_w(const float* __restrict__ w0,
                                              const float* __restrict__ w1,
                                              const float* __restrict__ w2,
                                              ushort* __restrict__ wb) {
  const int m = blockIdx.x >> 5;        // 0..55
  const int kc = blockIdx.x & 31;       // k-chunk of 8
  const int o = threadIdx.x;            // 0..255
  const float* src;
  if (m < 32)      src = w0 + ((size_t)(m * NO + o)) * NI;
  else if (m < 48) src = w1 + ((size_t)((m - 32) * NO + o)) * NI;
  else             src = w2 + ((size_t)((m - 48) * NO + o)) * NI;
  src += kc * 8;
  float4 a = *reinterpret_cast<const float4*>(src);
  float4 b = *reinterpret_cast<const float4*>(src + 4);
  u16x8 p = { f2bf(a.x), f2bf(a.y), f2bf(a.z), f2bf(a.w),
              f2bf(b.x), f2bf(b.y), f2bf(b.z), f2bf(b.w) };
  *reinterpret_cast<u16x8*>(wb + ((size_t)(blockIdx.x * 256 + o)) * 8) = p;  // 16B coalesced
}

// ---- main: block = [16 b] x [128 o (half)] x [CW c-tile], K in 4 stages of 64 via LDS ----
template<int CT>
DEVINL void tile_body(const float* __restrict__ x, const ushort* __restrict__ wb,
                      const float* __restrict__ bias0, float* __restrict__ out,
                      int bt, int oh, ushort* xs) {
  constexpr int c0 = CT * 16;
  constexpr int CW = (CT == 7) ? 8 : 16;   // c-tile 7 covers only c 112..119

  const int tid  = threadIdx.x;
  const int lane = tid & 63;
  const int wid  = tid >> 6;               // 8 waves, each owns 16 o-columns
  const int bg   = bt * 16;
  const int ocol = oh * 128 + wid * 16 + (lane & 15);

  const int rb = lane & 15;                // A-frag row (b)
  const int rg = lane >> 4;                // A/B-frag k-group

  // staging map: 4c x 16b per 16-lane group -> float4 loads, 16 full 64B lines/wave-instr
  const int cq = tid & 3;                  // c-quad
  const int sb = (tid >> 2) & 15;          // b row
  const int kslot = tid >> 6;              // k slot (== wid)

  f32x4 acc[CW];
#pragma unroll
  for (int i = 0; i < CW; ++i) acc[i] = (f32x4)0.0f;

#pragma unroll 1
  for (int s = 0; s < NSTAGE; ++s) {
    if (s) __syncthreads();                // all waves done reading xs before overwrite
    if (4 * cq < CW) {
#pragma unroll
      for (int it = 0; it < 2; ++it) {
        const int k0 = kslot * 4 + it * 32;            // 0..60 step 4
        const float* src = x + (size_t)(bg + sb) * (NI * NC)
                             + (size_t)(s * KQ + k0) * NC + (c0 + 4 * cq);
        f32x4 v0 = *reinterpret_cast<const f32x4*>(src);
        f32x4 v1 = *reinterpret_cast<const f32x4*>(src + NC);
        f32x4 v2 = *reinterpret_cast<const f32x4*>(src + 2 * NC);
        f32x4 v3 = *reinterpret_cast<const f32x4*>(src + 3 * NC);
#pragma unroll
        for (int c = 0; c < 4; ++c) {
          const int cc = 4 * cq + c;
          const int swz = ((sb & 7) ^ (cc & 7)) << 3;  // XOR bank swizzle on k
          const int kpos = k0 ^ swz;                   // stays 4-aligned
          ushort4 p;
          p.x = f2bf(v0[c]); p.y = f2bf(v1[c]); p.z = f2bf(v2[c]); p.w = f2bf(v3[c]);
          *reinterpret_cast<ushort4*>(xs + (cc * 16 + sb) * KQ + kpos) = p;
        }
      }
    }
    __syncthreads();

    bf16x8 bw0, bw1;                       // W fragments for the 2 k-chunks of this stage
#pragma unroll
    for (int cc = 0; cc < CW; ++cc) {
      const int c = c0 + cc;
      const int m = mat_of(c);
      const bool newm = (cc == 0) || (mat_of(c - 1) != m);   // folds at compile time
      if (newm) {
        // kc = s*8 + ks*4 + rg ; addr = ((m*32 + kc)*NO + ocol)*8
        const ushort* wp = wb + ((size_t)((m * 32 + s * 8 + rg) * NO + ocol)) * 8;
        bw0 = *reinterpret_cast<const bf16x8*>(wp);
        bw1 = *reinterpret_cast<const bf16x8*>(wp + (size_t)4 * NO * 8);
      }
      const ushort* xp = xs + (cc * 16 + rb) * KQ;
      const int swzr = ((rb & 7) ^ (cc & 7)) << 3;
      bf16x8 a0 = *reinterpret_cast<const bf16x8*>(xp + ((rg * 8) ^ swzr));
      acc[cc] = __builtin_amdgcn_mfma_f32_16x16x32_bf16(a0, bw0, acc[cc], 0, 0, 0);
      bf16x8 a1 = *reinterpret_cast<const bf16x8*>(xp + ((32 + rg * 8) ^ swzr));
      acc[cc] = __builtin_amdgcn_mfma_f32_16x16x32_bf16(a1, bw1, acc[cc], 0, 0, 0);
    }
  }

  if (CT < 2) {                             // l=0 irreps (c<32) carry bias b0[m=c][o]
#pragma unroll
    for (int cc = 0; cc < CW; ++cc) {
      float bv = bias0[(c0 + cc) * NO + ocol];
      acc[cc] += bv;
    }
  }

  const int br0 = bg + rg * 4;              // D row = (lane>>4)*4 + reg
#pragma unroll
  for (int r = 0; r < 4; ++r) {
#pragma unroll
    for (int q = 0; q < CW / 4; ++q) {      // 16B stores; thread owns full 64B c-line
      float4 v = make_float4(acc[4 * q + 0][r], acc[4 * q + 1][r],
                             acc[4 * q + 2][r], acc[4 * q + 3][r]);
      float* dst = out + ((size_t)(br0 + r) * NO + ocol) * NC + (c0 + 4 * q);
      *reinterpret_cast<float4*>(dst) = v;
    }
  }
}

__global__ __launch_bounds__(512, 4) void e3mix(const float* __restrict__ x,
                                                const ushort* __restrict__ wb,
                                                const float* __restrict__ bias0,
                                                float* __restrict__ out) {
  __shared__ ushort xs[16 * 16 * KQ];       // 32 KB
  const int bid = blockIdx.x;
  const int ct = bid & 7;                   // fastest -> per-XCD W locality (bid%8 ~ XCD)
  const int oh = (bid >> 3) & 1;
  const int bt = bid >> 4;                  // slowest -> b-slice temporal locality for x
  switch (ct) {
    case 0: tile_body<0>(x, wb, bias0, out, bt, oh, xs); break;
    case 1: tile_body<1>(x, wb, bias0, out, bt, oh, xs); break;
    case 2: tile_body<2>(x, wb, bias0, out, bt, oh, xs); break;
    case 3: tile_body<3>(x, wb, bias0, out, bt, oh, xs); break;
    case 4: tile_body<4>(x, wb, bias0, out, bt, oh, xs); break;
    case 5: tile_body<5>(x, wb, bias0, out, bt, oh, xs); break;
    case 6: tile_body<6>(x, wb, bias0, out, bt, oh, xs); break;
    default: tile_body<7>(x, wb, bias0, out, bt, oh, xs); break;
  }
}

extern "C" void kernel_launch(void* const* d_in, const int* in_sizes, int n_in,
                              void* d_out, int out_size, void* d_ws, size_t ws_size,
                              hipStream_t stream) {
  const float* x  = (const float*)d_in[0];
  const float* w0 = (const float*)d_in[1];
  const float* w1 = (const float*)d_in[2];
  const float* w2 = (const float*)d_in[3];
  const float* b0 = (const float*)d_in[4];
  float* out = (float*)d_out;
  ushort* wb = (ushort*)d_ws;               // needs 7.34 MB of scratch

  prep_w<<<56 * 32, 256, 0, stream>>>(w0, w1, w2, wb);
  e3mix<<<1024, 512, 0, stream>>>(x, wb, b0, out);
}